// Round 13
// baseline (98.386 us; speedup 1.0000x reference)
//
#include <hip/hip_runtime.h>
#include <cstdint>

#define CD 64
#define HWD 589824
#define NBLK 256
#define TPB 9                        // 256-col super-tiles per block
#define TCOLS 256
#define K1_ROWS (NBLK * TPB)         // 2304 cell rows
#define FMAXV 3.402823466e+38f

#define AS1 __attribute__((address_space(1)))
#define AS3 __attribute__((address_space(3)))

typedef float f32x16 __attribute__((ext_vector_type(16)));
typedef short bf16x8 __attribute__((ext_vector_type(8)));

__device__ __forceinline__ short f2bf(float f) {
    unsigned u = __float_as_uint(f);
    u = u + 0x7FFFu + ((u >> 16) & 1u);   // RNE
    return (short)(u >> 16);
}

// sorted top-4 insert: t.x <= t.y <= t.z <= t.w
__device__ __forceinline__ void ins4(float4& t, float x) {
    if (x < t.w) {
        if (x < t.z) { t.w = t.z;
            if (x < t.y) { t.z = t.y;
                if (x < t.x) { t.y = t.x; t.x = x; } else t.y = x;
            } else t.z = x;
        } else t.w = x;
    }
}

// kA: 64 blocks x 64 thr; thread k of block p loads one sel element.
__global__ __launch_bounds__(64) void kA_pack(
    const float* __restrict__ f1, const int* __restrict__ nidx,
    short* __restrict__ sel_bf, float* __restrict__ sel2,
    unsigned* __restrict__ ticket)
{
    const int p = blockIdx.x, k = threadIdx.x;
    if (p == 0 && k == 0) *ticket = 0u;
    float v = f1[(long)k * HWD + nidx[p]];
    float s = v * v;
#pragma unroll
    for (int off = 32; off; off >>= 1) s += __shfl_xor(s, off);
    sel_bf[p * CD + k] = f2bf(v);
    if (k == 0) sel2[p] = s;
}

// k1: 256 blocks (1/CU) x 512 thr. Double-buffered [64][256] f32 LDS tiles;
// each stage reads every k-row as ONE contiguous 1KB global_load_lds (wide
// DRAM bursts — the fix for the 128B-segment pattern that capped ~2.3TB/s).
// Counted vmcnt(8) pipeline, raw barriers. Per stage: 8 waves compute 32
// cols each via MFMA -> sorted top-4 per p -> lm merge -> one cells row.
__global__ __launch_bounds__(512, 1) void k1_topk(
    const float* __restrict__ f2, const short* __restrict__ sel_bf,
    const float* __restrict__ sel2, float4* __restrict__ cells)
{
    __shared__ float lds[2][CD][TCOLS];   // 128 KB
    __shared__ float4 lm[8][CD];          // 4 KB
    const int tid = threadIdx.x;
    const int lane = tid & 63, wid = tid >> 6;   // 8 waves
    const int l31 = lane & 31, lh = lane >> 5;
    const long nb = (long)blockIdx.x * (TPB * TCOLS);

    // wave wid stages rows [8*wid, 8*wid+8); one 1KB contiguous instr per row
#define STAGE(buf, c0) do {                                                 \
        _Pragma("unroll")                                                   \
        for (int kk = 0; kk < 8; ++kk) {                                    \
            int r_ = wid * 8 + kk;                                          \
            const float* gp_ = f2 + (long)r_ * HWD + (c0) + lane * 4;       \
            __builtin_amdgcn_global_load_lds((const AS1 void*)gp_,          \
                (AS3 void*)&lds[buf][r_][0], 16, 0, 0);                     \
        }                                                                   \
    } while (0)

    bf16x8 sf0[4], sf1[4];
#pragma unroll
    for (int ks = 0; ks < 4; ++ks) {
        sf0[ks] = *(const bf16x8*)(sel_bf + l31 * CD + 16 * ks + 8 * lh);
        sf1[ks] = *(const bf16x8*)(sel_bf + (l31 + 32) * CD + 16 * ks + 8 * lh);
    }
    const float sel20 = sel2[l31], sel21 = sel2[l31 + 32];
    __builtin_amdgcn_sched_barrier(0);

    STAGE(0, nb);                                   // stage 0 -> buf 0
    asm volatile("s_waitcnt vmcnt(0)" ::: "memory");
    __builtin_amdgcn_sched_barrier(0);
    __builtin_amdgcn_s_barrier();

    for (int t = 0; t < TPB; ++t) {
        const int cur = t & 1;
        if (t + 1 < TPB) {
            STAGE(cur ^ 1, nb + (long)(t + 1) * TCOLS);
            __builtin_amdgcn_sched_barrier(0);
            asm volatile("s_waitcnt vmcnt(8)" ::: "memory");  // stage t done; t+1 in flight
        } else {
            asm volatile("s_waitcnt vmcnt(0)" ::: "memory");
        }
        __builtin_amdgcn_sched_barrier(0);
        __builtin_amdgcn_s_barrier();               // barrier1: tile t ready; lm free
        __builtin_amdgcn_sched_barrier(0);

        const int col = wid * 32 + l31;
        float fs = 0.f;
        f32x16 a0, a1;
#pragma unroll
        for (int i = 0; i < 16; ++i) { a0[i] = 0.f; a1[i] = 0.f; }
#pragma unroll
        for (int ks = 0; ks < 4; ++ks) {
            bf16x8 af;
#pragma unroll
            for (int j = 0; j < 8; ++j) {
                float v = lds[cur][16 * ks + 8 * lh + j][col];
                fs += v * v;
                af[j] = f2bf(v);
            }
            a0 = __builtin_amdgcn_mfma_f32_32x32x16_bf16(af, sf0[ks], a0, 0, 0, 0);
            a1 = __builtin_amdgcn_mfma_f32_32x32x16_bf16(af, sf1[ks], a1, 0, 0, 0);
        }
        fs += __shfl_xor(fs, 32);                   // combine k-halves (same col)

        float4 tt = make_float4(FMAXV, FMAXV, FMAXV, FMAXV);
        float4 uu = tt;
#pragma unroll
        for (int i = 0; i < 16; ++i) {
            int r = (i & 3) + 8 * (i >> 2) + 4 * lh;
            float fr2 = __shfl(fs, r);
            ins4(tt, fmaxf(sel20 + fr2 - 2.f * a0[i], 0.f));   // p = l31
            ins4(uu, fmaxf(sel21 + fr2 - 2.f * a1[i], 0.f));   // p = l31+32
        }
        {   // merge the two lh halves (lanes l and l^32 hold the same p)
            float4 o;
            o.x = __shfl_xor(tt.x, 32); o.y = __shfl_xor(tt.y, 32);
            o.z = __shfl_xor(tt.z, 32); o.w = __shfl_xor(tt.w, 32);
            ins4(tt, o.x); ins4(tt, o.y); ins4(tt, o.z); ins4(tt, o.w);
            o.x = __shfl_xor(uu.x, 32); o.y = __shfl_xor(uu.y, 32);
            o.z = __shfl_xor(uu.z, 32); o.w = __shfl_xor(uu.w, 32);
            ins4(uu, o.x); ins4(uu, o.y); ins4(uu, o.z); ins4(uu, o.w);
        }
        if (lh == 0) { lm[wid][l31] = tt; lm[wid][l31 + 32] = uu; }
        asm volatile("s_waitcnt lgkmcnt(0)" ::: "memory");
        __builtin_amdgcn_sched_barrier(0);
        __builtin_amdgcn_s_barrier();               // barrier2: lm published; buf free
        __builtin_amdgcn_sched_barrier(0);

        if (wid == (t & 7)) {                       // rotate merge wave
            float4 m = lm[0][lane];
#pragma unroll
            for (int w = 1; w < 8; ++w) {
                float4 b = lm[w][lane];
                ins4(m, b.x); ins4(m, b.y); ins4(m, b.z); ins4(m, b.w);
            }
            cells[(long)(blockIdx.x * TPB + t) * CD + lane] = m;
        }
        // lm reads above finish before any wave's next lm write: the next
        // iteration's lm writes happen only after its barrier1, which the
        // merge wave reaches after finishing here.
    }
#undef STAGE
}

// k2: 64 blocks x 1024 thr; block p: per-thread sorted top-4 over its rows
// of cells[.][p], then 16 rounds of block-wide min extraction. Last finished
// block (ticket) does the deterministic ordered final sum.
__global__ __launch_bounds__(1024) void k2_sel(
    const float4* __restrict__ cells, float* __restrict__ partial,
    unsigned* __restrict__ ticket, float* __restrict__ out)
{
    const int p = blockIdx.x;
    const int tid = threadIdx.x;
    const int lane = tid & 63, wid = tid >> 6;
    __shared__ unsigned long long wmin[16];

    float4 b0 = cells[(long)tid * CD + p];
    float4 b1 = cells[(long)(tid + 1024) * CD + p];
    float4 b2 = (tid < K1_ROWS - 2048)
                ? cells[(long)(tid + 2048) * CD + p]
                : make_float4(FMAXV, FMAXV, FMAXV, FMAXV);

    float4 t = make_float4(FMAXV, FMAXV, FMAXV, FMAXV);
    ins4(t, b0.x); ins4(t, b0.y); ins4(t, b0.z); ins4(t, b0.w);
    ins4(t, b1.x); ins4(t, b1.y); ins4(t, b1.z); ins4(t, b1.w);
    ins4(t, b2.x); ins4(t, b2.y); ins4(t, b2.z); ins4(t, b2.w);

    float sum = 0.f;
    for (int rd = 0; rd < 16; ++rd) {
        unsigned long long key =
            ((unsigned long long)__float_as_uint(t.x) << 32) | (unsigned)tid;
#pragma unroll
        for (int off = 32; off; off >>= 1) {
            unsigned long long o = __shfl_xor(key, off);
            if (o < key) key = o;
        }
        if (lane == 0) wmin[wid] = key;
        __syncthreads();
        unsigned long long gk = wmin[0];
#pragma unroll
        for (int w = 1; w < 16; ++w) if (wmin[w] < gk) gk = wmin[w];
        sum += __uint_as_float((unsigned)(gk >> 32));
        if ((unsigned)(gk & 0xFFFFFFFFu) == (unsigned)tid) {
            t.x = t.y; t.y = t.z; t.z = t.w; t.w = FMAXV;   // pop local min
        }
        __syncthreads();
    }

    if (tid == 0) {
        partial[p] = sum;
        __threadfence();
        unsigned tk = atomicAdd(ticket, 1u);
        if (tk == CD - 1) {          // last block: deterministic ordered sum
            __threadfence();
            float s = 0.f;
            const volatile float* vp = partial;
            for (int q = 0; q < CD; ++q) s += vp[q];
            out[0] = -s / 1024.0f;
        }
    }
}

extern "C" void kernel_launch(void* const* d_in, const int* in_sizes, int n_in,
                              void* d_out, int out_size, void* d_ws, size_t ws_size,
                              hipStream_t stream)
{
    const float* f1   = (const float*)d_in[0];
    const float* f2   = (const float*)d_in[1];
    const int*   nidx = (const int*)d_in[3];     // negative_indices
    float* out = (float*)d_out;

    float4*   cells   = (float4*)d_ws;                          // 2304*64*16 = 2.36 MB
    short*    sel_bf  = (short*)(cells + (long)K1_ROWS * CD);   // 8 KB
    float*    sel2    = (float*)(sel_bf + CD * CD);
    float*    partial = sel2 + CD;
    unsigned* ticket  = (unsigned*)(partial + CD);

    kA_pack<<<CD,       64, 0, stream>>>(f1, nidx, sel_bf, sel2, ticket);
    k1_topk<<<NBLK,    512, 0, stream>>>(f2, sel_bf, sel2, cells);
    k2_sel <<<CD,     1024, 0, stream>>>(cells, partial, ticket, out);
}

// Round 14
// 85.667 us; speedup vs baseline: 1.1485x; 1.1485x over previous
//
#include <hip/hip_runtime.h>
#include <cstdint>

#define CD 64
#define HWD 589824
#define K1_BLOCKS 1536
#define K1_WAVES (K1_BLOCKS * 4)     // 6144
#define TPW 3                        // 32-col tiles per wave
#define K1_ROWS K1_WAVES             // one cells row per wave
#define FMAXV 3.402823466e+38f

typedef float f32x16 __attribute__((ext_vector_type(16)));
typedef short bf16x8 __attribute__((ext_vector_type(8)));

__device__ __forceinline__ short f2bf(float f) {
    unsigned u = __float_as_uint(f);
    u = u + 0x7FFFu + ((u >> 16) & 1u);   // RNE
    return (short)(u >> 16);
}

// sorted top-4 insert: t.x <= t.y <= t.z <= t.w
__device__ __forceinline__ void ins4(float4& t, float x) {
    if (x < t.w) {
        if (x < t.z) { t.w = t.z;
            if (x < t.y) { t.z = t.y;
                if (x < t.x) { t.y = t.x; t.x = x; } else t.y = x;
            } else t.z = x;
        } else t.w = x;
    }
}

// VGPR-streaming tile engine (R4-proven): 4 bursts of 8 independent
// 128B-coalesced loads, convert-as-you-load, MFMA from registers. No LDS.
__device__ __forceinline__ void tile_dist(
    const float* __restrict__ fp,          // f2 + n0 + l31
    const bf16x8* __restrict__ sf0, const bf16x8* __restrict__ sf1,
    int lh, f32x16& acc0, f32x16& acc1, float& fs)
{
    fs = 0.f;
#pragma unroll
    for (int i = 0; i < 16; ++i) { acc0[i] = 0.f; acc1[i] = 0.f; }
#pragma unroll
    for (int ks = 0; ks < 4; ++ks) {
        float av[8];
#pragma unroll
        for (int j = 0; j < 8; ++j)
            av[j] = fp[(long)(16 * ks + 8 * lh + j) * HWD];
        bf16x8 af;
#pragma unroll
        for (int j = 0; j < 8; ++j) {
            fs += av[j] * av[j];
            af[j] = f2bf(av[j]);
        }
        acc0 = __builtin_amdgcn_mfma_f32_32x32x16_bf16(af, sf0[ks], acc0, 0, 0, 0);
        acc1 = __builtin_amdgcn_mfma_f32_32x32x16_bf16(af, sf1[ks], acc1, 0, 0, 0);
    }
    fs += __shfl_xor(fs, 32);   // combine k-halves (same column n)
}

// kA: 64 blocks x 64 thr; thread k of block p loads one sel element.
__global__ __launch_bounds__(64) void kA_pack(
    const float* __restrict__ f1, const int* __restrict__ nidx,
    short* __restrict__ sel_bf, float* __restrict__ sel2,
    unsigned* __restrict__ ticket)
{
    const int p = blockIdx.x, k = threadIdx.x;
    if (p == 0 && k == 0) *ticket = 0u;
    float v = f1[(long)k * HWD + nidx[p]];
    float s = v * v;
#pragma unroll
    for (int off = 32; off; off >>= 1) s += __shfl_xor(s, off);
    sel_bf[p * CD + k] = f2bf(v);
    if (k == 0) sel2[p] = s;
}

// k1: 1536 blocks x 4 waves, VGPR streaming (no LDS, no barriers). Wave gw
// walks 3 contiguous 32-col tiles, keeps running sorted top-4 per p,
// lh-merges via shfl, stores one coalesced cells row.
__global__ __launch_bounds__(256) void k1_topk(
    const float* __restrict__ f2, const short* __restrict__ sel_bf,
    const float* __restrict__ sel2, float4* __restrict__ cells)
{
    const int tid = threadIdx.x;
    const int lane = tid & 63, wid = tid >> 6;
    const int l31 = lane & 31, lh = lane >> 5;
    const int gw = blockIdx.x * 4 + wid;        // 0..6143

    bf16x8 sf0[4], sf1[4];
#pragma unroll
    for (int ks = 0; ks < 4; ++ks) {
        sf0[ks] = *(const bf16x8*)(sel_bf + l31 * CD + 16 * ks + 8 * lh);
        sf1[ks] = *(const bf16x8*)(sel_bf + (l31 + 32) * CD + 16 * ks + 8 * lh);
    }
    const float sel20 = sel2[l31], sel21 = sel2[l31 + 32];

    float4 t = make_float4(FMAXV, FMAXV, FMAXV, FMAXV);
    float4 u = t;

#pragma unroll
    for (int tt = 0; tt < TPW; ++tt) {
        const long n0 = (long)(gw * TPW + tt) * 32;
        f32x16 a0, a1; float fs;
        tile_dist(f2 + n0 + l31, sf0, sf1, lh, a0, a1, fs);

#pragma unroll
        for (int i = 0; i < 16; ++i) {
            int r = (i & 3) + 8 * (i >> 2) + 4 * lh;
            float fr2 = __shfl(fs, r);
            ins4(t, fmaxf(sel20 + fr2 - 2.f * a0[i], 0.f));   // p = l31
            ins4(u, fmaxf(sel21 + fr2 - 2.f * a1[i], 0.f));   // p = l31+32
        }
    }

    // merge the two lh halves (lanes l and l^32 hold the same p)
    {
        float4 o;
        o.x = __shfl_xor(t.x, 32); o.y = __shfl_xor(t.y, 32);
        o.z = __shfl_xor(t.z, 32); o.w = __shfl_xor(t.w, 32);
        ins4(t, o.x); ins4(t, o.y); ins4(t, o.z); ins4(t, o.w);
        o.x = __shfl_xor(u.x, 32); o.y = __shfl_xor(u.y, 32);
        o.z = __shfl_xor(u.z, 32); o.w = __shfl_xor(u.w, 32);
        ins4(u, o.x); ins4(u, o.y); ins4(u, o.z); ins4(u, o.w);
    }
    if (lh == 0) {
        cells[(long)gw * CD + l31]      = t;   // p = l31
        cells[(long)gw * CD + l31 + 32] = u;   // p = l31+32
    }
}

// k2: 64 blocks x 1024 thr; block p: per-thread sorted top-4 over its 6
// rows of cells[.][p], then 16 rounds of block-wide min extraction. Last
// finished block (ticket) does the deterministic ordered final sum.
__global__ __launch_bounds__(1024) void k2_sel(
    const float4* __restrict__ cells, float* __restrict__ partial,
    unsigned* __restrict__ ticket, float* __restrict__ out)
{
    const int p = blockIdx.x;
    const int tid = threadIdx.x;
    const int lane = tid & 63, wid = tid >> 6;
    __shared__ unsigned long long wmin[16];

    float4 t = make_float4(FMAXV, FMAXV, FMAXV, FMAXV);
#pragma unroll
    for (int q = 0; q < K1_ROWS / 1024; ++q) {   // 6
        float4 b = cells[(long)(tid + q * 1024) * CD + p];
        ins4(t, b.x); ins4(t, b.y); ins4(t, b.z); ins4(t, b.w);
    }

    float sum = 0.f;
    for (int rd = 0; rd < 16; ++rd) {
        unsigned long long key =
            ((unsigned long long)__float_as_uint(t.x) << 32) | (unsigned)tid;
#pragma unroll
        for (int off = 32; off; off >>= 1) {
            unsigned long long o = __shfl_xor(key, off);
            if (o < key) key = o;
        }
        if (lane == 0) wmin[wid] = key;
        __syncthreads();
        unsigned long long gk = wmin[0];
#pragma unroll
        for (int w = 1; w < 16; ++w) if (wmin[w] < gk) gk = wmin[w];
        sum += __uint_as_float((unsigned)(gk >> 32));
        if ((unsigned)(gk & 0xFFFFFFFFu) == (unsigned)tid) {
            t.x = t.y; t.y = t.z; t.z = t.w; t.w = FMAXV;   // pop local min
        }
        __syncthreads();
    }

    if (tid == 0) {
        partial[p] = sum;
        __threadfence();
        unsigned tk = atomicAdd(ticket, 1u);
        if (tk == CD - 1) {          // last block: deterministic ordered sum
            __threadfence();
            float s = 0.f;
            const volatile float* vp = partial;
            for (int q = 0; q < CD; ++q) s += vp[q];
            out[0] = -s / 1024.0f;
        }
    }
}

extern "C" void kernel_launch(void* const* d_in, const int* in_sizes, int n_in,
                              void* d_out, int out_size, void* d_ws, size_t ws_size,
                              hipStream_t stream)
{
    const float* f1   = (const float*)d_in[0];
    const float* f2   = (const float*)d_in[1];
    const int*   nidx = (const int*)d_in[3];     // negative_indices
    float* out = (float*)d_out;

    float4*   cells   = (float4*)d_ws;                          // 6144*64*16 = 6.3 MB
    short*    sel_bf  = (short*)(cells + (long)K1_ROWS * CD);   // 8 KB
    float*    sel2    = (float*)(sel_bf + CD * CD);
    float*    partial = sel2 + CD;
    unsigned* ticket  = (unsigned*)(partial + CD);

    kA_pack<<<CD,         64, 0, stream>>>(f1, nidx, sel_bf, sel2, ticket);
    k1_topk<<<K1_BLOCKS, 256, 0, stream>>>(f2, sel_bf, sel2, cells);
    k2_sel <<<CD,       1024, 0, stream>>>(cells, partial, ticket, out);
}

// Round 15
// 84.370 us; speedup vs baseline: 1.1661x; 1.0154x over previous
//
#include <hip/hip_runtime.h>
#include <cstdint>

#define CD 64
#define HWD 589824
#define K1_BLOCKS 1152
#define TPB 4                        // 128-col tiles per block (512-col span)
#define K1_ROWS (K1_BLOCKS * 4)      // 4608 cell rows (one per wave)
#define FMAXV 3.402823466e+38f

typedef float f32x16 __attribute__((ext_vector_type(16)));
typedef short bf16x8 __attribute__((ext_vector_type(8)));

__device__ __forceinline__ short f2bf(float f) {
    unsigned u = __float_as_uint(f);
    u = u + 0x7FFFu + ((u >> 16) & 1u);   // RNE
    return (short)(u >> 16);
}

// sorted top-4 insert: t.x <= t.y <= t.z <= t.w
__device__ __forceinline__ void ins4(float4& t, float x) {
    if (x < t.w) {
        if (x < t.z) { t.w = t.z;
            if (x < t.y) { t.z = t.y;
                if (x < t.x) { t.y = t.x; t.x = x; } else t.y = x;
            } else t.z = x;
        } else t.w = x;
    }
}

// kA: 64 blocks x 64 thr; thread k of block p loads one sel element.
__global__ __launch_bounds__(64) void kA_pack(
    const float* __restrict__ f1, const int* __restrict__ nidx,
    short* __restrict__ sel_bf, float* __restrict__ sel2,
    unsigned* __restrict__ ticket)
{
    const int p = blockIdx.x, k = threadIdx.x;
    if (p == 0 && k == 0) *ticket = 0u;
    float v = f1[(long)k * HWD + nidx[p]];
    float s = v * v;
#pragma unroll
    for (int off = 32; off; off >>= 1) s += __shfl_xor(s, off);
    sel_bf[p * CD + k] = f2bf(v);
    if (k == 0) sel2[p] = s;
}

// k1: 1152 blocks x 256 thr. Reg-staged async pipeline:
//   issue 8 float4 loads (512B contiguous per instr, 2 rows) for tile t+1
//   -> compute tile t from 32KB LDS f32 [64][128] via MFMA -> top-4
//   -> raw barrier (lgkmcnt only; staging loads stay in flight)
//   -> ds_write staged regs (compiler inserts the vmcnt wait).
__global__ __launch_bounds__(256) void k1_topk(
    const float* __restrict__ f2, const short* __restrict__ sel_bf,
    const float* __restrict__ sel2, float4* __restrict__ cells)
{
    __shared__ float lds[CD][128];   // 32 KB
    const int tid = threadIdx.x;
    const int lane = tid & 63, wid = tid >> 6;
    const int l31 = lane & 31, lh = lane >> 5;
    const long nb = (long)blockIdx.x * (TPB * 128);

    const int srow = tid >> 5;          // 0..7: row offset within 8-row group
    const int scol = (tid & 31) * 4;    // float4 column (elements)

    bf16x8 sf0[4], sf1[4];
#pragma unroll
    for (int ks = 0; ks < 4; ++ks) {
        sf0[ks] = *(const bf16x8*)(sel_bf + l31 * CD + 16 * ks + 8 * lh);
        sf1[ks] = *(const bf16x8*)(sel_bf + (l31 + 32) * CD + 16 * ks + 8 * lh);
    }
    const float sel20 = sel2[l31], sel21 = sel2[l31 + 32];

    float4 st[8];
    // prologue: load + write tile 0
#pragma unroll
    for (int i = 0; i < 8; ++i)
        st[i] = *(const float4*)(f2 + (long)(8 * i + srow) * HWD + nb + scol);
    __builtin_amdgcn_sched_barrier(0);
#pragma unroll
    for (int i = 0; i < 8; ++i)
        *(float4*)&lds[8 * i + srow][scol] = st[i];

    float4 t = make_float4(FMAXV, FMAXV, FMAXV, FMAXV);
    float4 u = t;

#pragma unroll
    for (int tt = 0; tt < TPB; ++tt) {
        // issue next tile's loads early (latency hides under compute)
        if (tt + 1 < TPB) {
#pragma unroll
            for (int i = 0; i < 8; ++i)
                st[i] = *(const float4*)(f2 + (long)(8 * i + srow) * HWD
                                         + nb + (long)(tt + 1) * 128 + scol);
            __builtin_amdgcn_sched_barrier(0);
        }
        // publish the ds_writes of tile tt (lgkm only — vmem stays in flight)
        asm volatile("s_waitcnt lgkmcnt(0)" ::: "memory");
        __builtin_amdgcn_sched_barrier(0);
        __builtin_amdgcn_s_barrier();
        __builtin_amdgcn_sched_barrier(0);

        // compute tile tt
        const int col = wid * 32 + l31;
        float fs = 0.f;
        f32x16 a0, a1;
#pragma unroll
        for (int i = 0; i < 16; ++i) { a0[i] = 0.f; a1[i] = 0.f; }
#pragma unroll
        for (int ks = 0; ks < 4; ++ks) {
            bf16x8 af;
#pragma unroll
            for (int j = 0; j < 8; ++j) {
                float v = lds[16 * ks + 8 * lh + j][col];
                fs += v * v;
                af[j] = f2bf(v);
            }
            a0 = __builtin_amdgcn_mfma_f32_32x32x16_bf16(af, sf0[ks], a0, 0, 0, 0);
            a1 = __builtin_amdgcn_mfma_f32_32x32x16_bf16(af, sf1[ks], a1, 0, 0, 0);
        }
        fs += __shfl_xor(fs, 32);       // combine k-halves (same col)

#pragma unroll
        for (int i = 0; i < 16; ++i) {
            int r = (i & 3) + 8 * (i >> 2) + 4 * lh;
            float fr2 = __shfl(fs, r);
            ins4(t, fmaxf(sel20 + fr2 - 2.f * a0[i], 0.f));   // p = l31
            ins4(u, fmaxf(sel21 + fr2 - 2.f * a1[i], 0.f));   // p = l31+32
        }

        // everyone done reading tile tt -> buffer free for the next writes
        asm volatile("s_waitcnt lgkmcnt(0)" ::: "memory");
        __builtin_amdgcn_sched_barrier(0);
        __builtin_amdgcn_s_barrier();
        __builtin_amdgcn_sched_barrier(0);

        if (tt + 1 < TPB) {
#pragma unroll
            for (int i = 0; i < 8; ++i)
                *(float4*)&lds[8 * i + srow][scol] = st[i];   // waits its vmcnt
        }
    }

    // merge the two lh halves (lanes l and l^32 hold the same p)
    {
        float4 o;
        o.x = __shfl_xor(t.x, 32); o.y = __shfl_xor(t.y, 32);
        o.z = __shfl_xor(t.z, 32); o.w = __shfl_xor(t.w, 32);
        ins4(t, o.x); ins4(t, o.y); ins4(t, o.z); ins4(t, o.w);
        o.x = __shfl_xor(u.x, 32); o.y = __shfl_xor(u.y, 32);
        o.z = __shfl_xor(u.z, 32); o.w = __shfl_xor(u.w, 32);
        ins4(u, o.x); ins4(u, o.y); ins4(u, o.z); ins4(u, o.w);
    }
    if (lh == 0) {
        const int gw = blockIdx.x * 4 + wid;
        cells[(long)gw * CD + l31]      = t;   // p = l31
        cells[(long)gw * CD + l31 + 32] = u;   // p = l31+32
    }
}

// k2: 64 blocks x 1024 thr; block p: per-thread sorted top-4 over its rows
// of cells[.][p], then 16 rounds of block-wide min extraction. Last finished
// block (ticket) does the deterministic ordered final sum.
__global__ __launch_bounds__(1024) void k2_sel(
    const float4* __restrict__ cells, float* __restrict__ partial,
    unsigned* __restrict__ ticket, float* __restrict__ out)
{
    const int p = blockIdx.x;
    const int tid = threadIdx.x;
    const int lane = tid & 63, wid = tid >> 6;
    __shared__ unsigned long long wmin[16];

    float4 t = make_float4(FMAXV, FMAXV, FMAXV, FMAXV);
#pragma unroll
    for (int q = 0; q < 4; ++q) {
        float4 b = cells[(long)(tid + q * 1024) * CD + p];
        ins4(t, b.x); ins4(t, b.y); ins4(t, b.z); ins4(t, b.w);
    }
    if (tid < K1_ROWS - 4096) {   // 512
        float4 b = cells[(long)(tid + 4096) * CD + p];
        ins4(t, b.x); ins4(t, b.y); ins4(t, b.z); ins4(t, b.w);
    }

    float sum = 0.f;
    for (int rd = 0; rd < 16; ++rd) {
        unsigned long long key =
            ((unsigned long long)__float_as_uint(t.x) << 32) | (unsigned)tid;
#pragma unroll
        for (int off = 32; off; off >>= 1) {
            unsigned long long o = __shfl_xor(key, off);
            if (o < key) key = o;
        }
        if (lane == 0) wmin[wid] = key;
        __syncthreads();
        unsigned long long gk = wmin[0];
#pragma unroll
        for (int w = 1; w < 16; ++w) if (wmin[w] < gk) gk = wmin[w];
        sum += __uint_as_float((unsigned)(gk >> 32));
        if ((unsigned)(gk & 0xFFFFFFFFu) == (unsigned)tid) {
            t.x = t.y; t.y = t.z; t.z = t.w; t.w = FMAXV;   // pop local min
        }
        __syncthreads();
    }

    if (tid == 0) {
        partial[p] = sum;
        __threadfence();
        unsigned tk = atomicAdd(ticket, 1u);
        if (tk == CD - 1) {          // last block: deterministic ordered sum
            __threadfence();
            float s = 0.f;
            const volatile float* vp = partial;
            for (int q = 0; q < CD; ++q) s += vp[q];
            out[0] = -s / 1024.0f;
        }
    }
}

extern "C" void kernel_launch(void* const* d_in, const int* in_sizes, int n_in,
                              void* d_out, int out_size, void* d_ws, size_t ws_size,
                              hipStream_t stream)
{
    const float* f1   = (const float*)d_in[0];
    const float* f2   = (const float*)d_in[1];
    const int*   nidx = (const int*)d_in[3];     // negative_indices
    float* out = (float*)d_out;

    float4*   cells   = (float4*)d_ws;                          // 4608*64*16 = 4.7 MB
    short*    sel_bf  = (short*)(cells + (long)K1_ROWS * CD);   // 8 KB
    float*    sel2    = (float*)(sel_bf + CD * CD);
    float*    partial = sel2 + CD;
    unsigned* ticket  = (unsigned*)(partial + CD);

    kA_pack<<<CD,         64, 0, stream>>>(f1, nidx, sel_bf, sel2, ticket);
    k1_topk<<<K1_BLOCKS, 256, 0, stream>>>(f2, sel_bf, sel2, cells);
    k2_sel <<<CD,       1024, 0, stream>>>(cells, partial, ticket, out);
}